// Round 14
// baseline (555.871 us; speedup 1.0000x reference)
//
#include <hip/hip_runtime.h>

// Problem constants
#define TP 512   // passage length
#define TB 8     // batch
#define TD 256   // input size
#define TH 75    // attn hidden
#define THP 80   // padded attn hidden (float4-friendly, pads zeroed)
#define TO 128   // GRU hidden

// 2*log2(e): folded into Wv1/Wv2T by wv12 so score's sigmoid uses raw v_exp_f32
#define LOG2E2 2.8853900817779268f

// flag region layout (uints, each slot padded to its own 256B line)
#define FLAG_SCNT 0        // 64 counters (score jt done-count, 8 arrivals each)
#define FLAG_DONE 4096     // 8 counters  (gatexp completion, 16 arrivals each)
#define FLAG_GF   4608     // 128 flags   (gatexp block gb done)
#define FLAG_TOTAL 12800   // uints

typedef _Float16 half_t;
typedef _Float16 half2v __attribute__((ext_vector_type(2)));
typedef _Float16 half4v __attribute__((ext_vector_type(4)));
typedef _Float16 half8v __attribute__((ext_vector_type(8)));
typedef float    float4v __attribute__((ext_vector_type(4)));

__device__ __forceinline__ float fast_rcp(float x) { return __builtin_amdgcn_rcpf(x); }
__device__ __forceinline__ float ex2(float x) {
#if __has_builtin(__builtin_amdgcn_exp2f)
    return __builtin_amdgcn_exp2f(x);
#else
    float r; asm("v_exp_f32 %0, %1" : "=v"(r) : "v"(x)); return r;
#endif
}
__device__ __forceinline__ float fast_tanh(float x) {
    return 1.0f - 2.0f * fast_rcp(1.0f + __expf(2.0f * x));
}
__device__ __forceinline__ float fast_sigmoid(float x) {
    return fast_rcp(1.0f + __expf(-x));
}
__device__ __forceinline__ float fdot2h(half2v a, half2v b, float c) {
#if __has_builtin(__builtin_amdgcn_fdot2)
    return __builtin_amdgcn_fdot2(a, b, c, false);
#else
    return c + (float)a[0] * (float)b[0] + (float)a[1] * (float)b[1];
#endif
}
#define EXT2(v, j) __builtin_shufflevector((v), (v), 2*(j), 2*(j)+1)
__device__ __forceinline__ void dot3_h8(half8v wr, half8v wz, half8v wn, half8v h,
                                        float& ar, float& az, float& an) {
    half2v h0 = EXT2(h, 0), h1 = EXT2(h, 1), h2 = EXT2(h, 2), h3 = EXT2(h, 3);
    ar = fdot2h(EXT2(wr, 0), h0, ar);
    az = fdot2h(EXT2(wz, 0), h0, az);
    an = fdot2h(EXT2(wn, 0), h0, an);
    ar = fdot2h(EXT2(wr, 1), h1, ar);
    az = fdot2h(EXT2(wz, 1), h1, az);
    an = fdot2h(EXT2(wn, 1), h1, an);
    ar = fdot2h(EXT2(wr, 2), h2, ar);
    az = fdot2h(EXT2(wz, 2), h2, az);
    an = fdot2h(EXT2(wn, 2), h2, an);
    ar = fdot2h(EXT2(wr, 3), h3, ar);
    az = fdot2h(EXT2(wz, 3), h3, az);
    an = fdot2h(EXT2(wn, 3), h3, an);
}
__device__ __forceinline__ float pair_sum_dpp(float v) {
    int i1 = __builtin_amdgcn_update_dpp(0, __builtin_bit_cast(int, v), 0xB1, 0xF, 0xF, true);
    return v + __builtin_bit_cast(float, i1);
}
__device__ __forceinline__ half8v cvt8(float4 f0, float4 f1) {
    return (half8v){(half_t)f0.x,(half_t)f0.y,(half_t)f0.z,(half_t)f0.w,
                    (half_t)f1.x,(half_t)f1.y,(half_t)f1.z,(half_t)f1.w};
}

// ------- prep: re-grained to 8 elems/thread (R25) + fused vtrans ------------
// R22 decomposition showed prep ~50us at a ~10us traffic roofline -> the 7459
// trivial blocks were dispatch-rate-bound. Now 907 work blocks (8 consecutive
// elements per thread, float4x2 -> half8) + 256 vtrans blocks = 1163 total.
// Also zeroes the tail_kernel flag region each iteration.
__global__ __launch_bounds__(256) void prep_kernel(
    const float* __restrict__ v,
    const float* __restrict__ Wvp1, const float* __restrict__ Wvp2,
    const float* __restrict__ Wg,   const float* __restrict__ wihf,
    const float* __restrict__ wihb, const float* __restrict__ bihf,
    const float* __restrict__ bihb, const float* __restrict__ whhf,
    const float* __restrict__ whhb,
    float* __restrict__ bihC,
    half_t* __restrict__ v16, half_t* __restrict__ g16,
    half_t* __restrict__ Wg16B, half_t* __restrict__ Wih16B,
    half_t* __restrict__ whh16, half_t* __restrict__ WT16B,
    half_t* __restrict__ vT16, unsigned* __restrict__ flags)
{
    __shared__ half_t lt[64 * 66];   // vtrans tile [d_local][p_local], stride 66

    if (blockIdx.x >= 907) {                     // ---- fused vtrans blocks ----
        int vb = blockIdx.x - 907;               // 0..255
        int t = threadIdx.x;
        int b  = vb >> 5;
        int pt = (vb >> 2) & 7;
        int dt = vb & 3;
        {
            int pl = t >> 2, dseg = (t & 3) * 16;
            const float4* src = (const float4*)(v + (((pt * 64 + pl) * 8 + b) << 8) + dt * 64 + dseg);
            float4 f0 = src[0], f1 = src[1], f2 = src[2], f3 = src[3];
            half_t hv[16] = {
                (half_t)f0.x,(half_t)f0.y,(half_t)f0.z,(half_t)f0.w,
                (half_t)f1.x,(half_t)f1.y,(half_t)f1.z,(half_t)f1.w,
                (half_t)f2.x,(half_t)f2.y,(half_t)f2.z,(half_t)f2.w,
                (half_t)f3.x,(half_t)f3.y,(half_t)f3.z,(half_t)f3.w };
#pragma unroll
            for (int u = 0; u < 16; ++u) lt[(dseg + u) * 66 + pl] = hv[u];
        }
        __syncthreads();
        {
            int dl = t >> 2, pseg = (t & 3) * 16;
            half8v h0 = *(const half8v*)(lt + dl * 66 + pseg);
            half8v h1 = *(const half8v*)(lt + dl * 66 + pseg + 8);
            half8v* dst = (half8v*)(vT16 + ((b * 256 + dt * 64 + dl) << 9) + pt * 64 + pseg);
            dst[0] = h0; dst[1] = h1;
        }
        return;
    }

    int t8 = blockIdx.x * 256 + threadIdx.x;     // task id (8 elems each)
    if (t8 < 131072) {                           // v cast + g16 first half
        int base = t8 * 8;
        const float4* vp = (const float4*)(v + base);
        half8v hv = cvt8(vp[0], vp[1]);
        *(half8v*)(v16 + base) = hv;
        int row = base >> 8, d0 = base & 255;
        *(half8v*)(g16 + row * 512 + d0) = hv;
        return;
    }
    t8 -= 131072;
    if (t8 < 96) {                               // bihC concat
        int base = t8 * 8;
#pragma unroll
        for (int u = 0; u < 8; ++u) {
            int id = base + u;
            bihC[id] = (id < 384) ? bihf[id] : bihb[id - 384];
        }
        return;
    }
    t8 -= 96;
    if (t8 < 32768) {                            // Wg16B frags (8 j's = 8 consec k's)
        int base = t8 * 8;
        int lane = (base >> 3) & 63, kt = (base >> 9) & 15, nt = base >> 13;
        int o = nt * 16 + (lane & 15);
        int k0 = kt * 32 + ((lane >> 4) << 3);
        const float4* sp = (const float4*)(Wg + o * 512 + k0);
        *(half8v*)(Wg16B + base) = cvt8(sp[0], sp[1]);
        return;
    }
    t8 -= 32768;
    if (t8 < 49152) {                            // Wih16B frags
        int base = t8 * 8;
        int lane = (base >> 3) & 63, kt = (base >> 9) & 15, nt = base >> 13;
        int o = nt * 16 + (lane & 15);
        int k0 = kt * 32 + ((lane >> 4) << 3);
        const float4* sp = (const float4*)(((o < 384) ? (wihf + o * 512) : (wihb + (o - 384) * 512)) + k0);
        *(half8v*)(Wih16B + base) = cvt8(sp[0], sp[1]);
        return;
    }
    t8 -= 49152;
    if (t8 < 12288) {                            // whh16 linear copy
        int base = t8 * 8;
        int d = (base >= 49152) ? 1 : 0;
        int i0 = base - d * 49152;
        const float4* sp = (const float4*)((d ? whhb : whhf) + i0);
        *(half8v*)(whh16 + base) = cvt8(sp[0], sp[1]);
        return;
    }
    t8 -= 12288;
    if (t8 < 5120) {                             // WT16B frags [Wvp1;Wvp2]
        int base = t8 * 8;
        int lane = (base >> 3) & 63, kt = (base >> 9) & 7, nt = base >> 12;
        int o = nt * 16 + (lane & 15);
        int k0 = kt * 32 + ((lane >> 4) << 3);
        half8v hv = (half8v){(half_t)0,(half_t)0,(half_t)0,(half_t)0,
                             (half_t)0,(half_t)0,(half_t)0,(half_t)0};
        if (o < 75) {
            const float4* sp = (const float4*)(Wvp1 + o * 256 + k0);
            hv = cvt8(sp[0], sp[1]);
        } else if (o < 150) {
            const float4* sp = (const float4*)(Wvp2 + (o - 75) * 256 + k0);
            hv = cvt8(sp[0], sp[1]);
        }
        *(half8v*)(WT16B + base) = hv;
        return;
    }
    t8 -= 5120;
    if (t8 < 1600) {                             // zero flag region
        int base = t8 * 8;
#pragma unroll
        for (int u = 0; u < 8; ++u) flags[base + u] = 0u;
    }
}

// ---------------- Wv1/Wv2T via MFMA: [4096,160] = v16 @ WT16B ---------------
__global__ __launch_bounds__(128) void wv12_kernel(
    const half_t* __restrict__ v16, const half_t* __restrict__ WT16B,
    float* __restrict__ Wv1, float* __restrict__ Wv2T)
{
    int tid = threadIdx.x;
    int lane = tid & 63, w = tid >> 6;
    int l15 = lane & 15, quad = lane >> 4;
    int r0 = blockIdx.x * 16;

    float4v acc[5];
#pragma unroll
    for (int n5 = 0; n5 < 5; ++n5) acc[n5] = (float4v){0.f, 0.f, 0.f, 0.f};

#pragma unroll
    for (int kt = 0; kt < 8; ++kt) {
        half8v a = *(const half8v*)(v16 + (r0 + l15) * 256 + kt * 32 + quad * 8);
#pragma unroll
        for (int n5 = 0; n5 < 5; ++n5) {
            int nt = w * 5 + n5;
            half8v b = *(const half8v*)(WT16B + ((nt * 8 + kt) * 64 + lane) * 8);
            acc[n5] = __builtin_amdgcn_mfma_f32_16x16x32_f16(a, b, acc[n5], 0, 0, 0);
        }
    }
#pragma unroll
    for (int n5 = 0; n5 < 5; ++n5) {
        int col = (w * 5 + n5) * 16 + l15;
#pragma unroll
        for (int r = 0; r < 4; ++r) {
            int row = r0 + quad * 4 + r;
            int p = row >> 3, b = row & 7;
            int ob = (b * TP + p) * THP;
            float val2 = LOG2E2 * acc[n5][r];
            if (col < 75)       Wv1[ob + col] = val2;
            else if (col < 80)  { Wv1[ob + col] = 0.0f;
                                  Wv2T[(b * THP + col - 75) * TP + p] = val2; }
            else if (col < 150) Wv2T[(b * THP + col - 75) * TP + p] = val2;
            else if (col < 155) Wv2T[(b * THP + col - 75) * TP + p] = 0.0f;
        }
    }
}

// ------ tail: score+context (512) | gatexp (128) | gru (16) in ONE kernel ----
// R25: producer-consumer via set-once per-line flags (NOT barriers; R22's
// 70us/barrier was 512 RMWs on one line — here max 16 arrivals/line).
//   score sb: computes a[b,jt*8..+8] + fused context -> g16; release scnt[jt].
//   gatexp gb: waits scnt[gb>>1]==8; computes xp rows; release gflag[gb],
//              done[gb&7].
//   gru ci: per macro-step waits the 2 gflags covering its positions; once
//           sum(done)==128 observed (acquire), skips all polling.
// Deadlock-free: __launch_bounds__(256,3) + LDS 36160 -> >=3 blocks/CU ->
// 768 slots >= 656 blocks, ALL co-resident; producers have lower blockIdx.
__global__ __launch_bounds__(256, 3) void tail_kernel(
    const float* __restrict__ Wv1, const float* __restrict__ Wv2T,
    const float* __restrict__ vw, const half_t* __restrict__ vT16,
    half_t* __restrict__ g16,
    const half_t* __restrict__ Wg16B, const half_t* __restrict__ Wih16B,
    const float* __restrict__ bihC,
    float* __restrict__ xpf, float* __restrict__ xpb,
    const half_t* __restrict__ whh16,
    const float* __restrict__ bhhf, const float* __restrict__ bhhb,
    float* __restrict__ out, unsigned* __restrict__ flags)
{
    __shared__ __align__(16) unsigned char smem[36160];
    int tid = threadIdx.x;
    int lane = tid & 63, w = tid >> 6;
    int l15 = lane & 15, quad = lane >> 4;
    unsigned bid = blockIdx.x;

    if (bid < 512) {
        // ================= score + fused context =================
        int b  = bid >> 6;
        int j0 = (bid & 63) * 8;
        half_t* aL  = (half_t*)smem;                    // 16*528 halfs = 16896B
        float* wv1j = (float*)(smem + 16896);           // 8*THP = 2560B
        float* vws  = (float*)(smem + 19456);           // THP   = 320B
        float* sc   = (float*)(smem + 19776);           // 8*TP  = 16384B

        for (int e = tid; e < 8 * 528; e += 256) aL[8 * 528 + e] = (half_t)0.0f;

        if (tid < THP) vws[tid] = (tid < TH) ? vw[tid] : 0.0f;
        for (int e = tid; e < 8 * THP; e += 256) {
            int jj = e / THP, k = e - jj * THP;
            wv1j[e] = Wv1[(b * TP + j0 + jj) * THP + k];
        }
        __syncthreads();

        float Csum = 0.0f;
        {
            const float4* c4 = (const float4*)vws;
            for (int kk = 0; kk < 20; ++kk) { float4 c = c4[kk]; Csum += c.x + c.y + c.z + c.w; }
        }

        int i0 = tid, i1 = tid + 256;
        float acc0[8] = {0.f,0.f,0.f,0.f,0.f,0.f,0.f,0.f};
        float acc1[8] = {0.f,0.f,0.f,0.f,0.f,0.f,0.f,0.f};
        const float* wvt = Wv2T + b * THP * TP;
#pragma unroll
        for (int kt = 0; kt < 5; ++kt) {
            float r0v[16], r1v[16];
#pragma unroll
            for (int u = 0; u < 16; ++u) {
                const float* colp = wvt + (kt * 16 + u) * TP;
                r0v[u] = colp[i0];
                r1v[u] = colp[i1];
            }
            const float* cp = vws + kt * 16;
#pragma unroll
            for (int jj = 0; jj < 8; ++jj) {
                const float* w1 = wv1j + jj * THP + kt * 16;
                float s0 = 0.f, s1 = 0.f;
#pragma unroll
                for (int u = 0; u < 16; ++u) {
                    float cu = cp[u], wu = w1[u];
                    s0 += cu * fast_rcp(1.0f + ex2(r0v[u] + wu));
                    s1 += cu * fast_rcp(1.0f + ex2(r1v[u] + wu));
                }
                acc0[jj] += s0; acc1[jj] += s1;
            }
        }
#pragma unroll
        for (int jj = 0; jj < 8; ++jj) {
            sc[jj * TP + i0] = Csum - 2.0f * acc0[jj];
            sc[jj * TP + i1] = Csum - 2.0f * acc1[jj];
        }
        __syncthreads();

#pragma unroll
        for (int ps = 0; ps < 2; ++ps) {
            int jj = (tid >> 6) + ps * 4, l = tid & 63;
            float m = -1e30f;
#pragma unroll
            for (int q = 0; q < 8; ++q) m = fmaxf(m, sc[jj * TP + l + q * 64]);
#pragma unroll
            for (int s = 32; s > 0; s >>= 1) m = fmaxf(m, __shfl_xor(m, s));
            float e[8];
            float sum = 0.0f;
#pragma unroll
            for (int q = 0; q < 8; ++q) { e[q] = __expf(sc[jj * TP + l + q * 64] - m); sum += e[q]; }
#pragma unroll
            for (int s = 32; s > 0; s >>= 1) sum += __shfl_xor(sum, s);
            float inv = fast_rcp(sum);
#pragma unroll
            for (int q = 0; q < 8; ++q) aL[jj * 528 + l + q * 64] = (half_t)(e[q] * inv);
        }
        __syncthreads();

        {   // fused context
            const half_t* vbase = vT16 + ((b * 256) << 9);
            float4v acc[4];
#pragma unroll
            for (int nti = 0; nti < 4; ++nti) acc[nti] = (float4v){0.f, 0.f, 0.f, 0.f};
#pragma unroll 4
            for (int kt = 0; kt < 16; ++kt) {
                half8v a = *(const half8v*)(aL + l15 * 528 + kt * 32 + quad * 8);
#pragma unroll
                for (int nti = 0; nti < 4; ++nti) {
                    int d = (w * 4 + nti) * 16 + l15;
                    half8v bb = *(const half8v*)(vbase + (d << 9) + kt * 32 + quad * 8);
                    acc[nti] = __builtin_amdgcn_mfma_f32_16x16x32_f16(a, bb, acc[nti], 0, 0, 0);
                }
            }
            int jl0 = quad * 4;
            if (jl0 < 8) {
#pragma unroll
                for (int nti = 0; nti < 4; ++nti) {
                    int d = (w * 4 + nti) * 16 + l15;
#pragma unroll
                    for (int r = 0; r < 4; ++r) {
                        int j = j0 + jl0 + r;
                        g16[(j * TB + b) * 512 + 256 + d] = (half_t)acc[nti][r];
                    }
                }
            }
        }
        __syncthreads();   // drain g16 stores (vmcnt 0) before release
        if (tid == 0)
            __hip_atomic_fetch_add(flags + FLAG_SCNT + (bid & 63) * 64, 1u,
                                   __ATOMIC_RELEASE, __HIP_MEMORY_SCOPE_AGENT);

    } else if (bid < 640) {
        // ================= gatexp =================
        int gb = (int)bid - 512;
        if (tid == 0) {
            while (__hip_atomic_load(flags + FLAG_SCNT + (gb >> 1) * 64,
                                     __ATOMIC_ACQUIRE, __HIP_MEMORY_SCOPE_AGENT) < 8u)
                __builtin_amdgcn_s_sleep(16);
        }
        __syncthreads();

        half_t* gA = (half_t*)smem;          // 32 x 520 halfs = 33280B
        int r0 = gb * 32;

        for (int e = tid; e < 2048; e += 256) {
            int row = e >> 6, c8 = e & 63;
            *(half8v*)(gA + row * 520 + c8 * 8) =
                *(const half8v*)(g16 + (r0 + row) * 512 + c8 * 8);
        }
        __syncthreads();

        float4v acc[2][8];
#pragma unroll
        for (int mi = 0; mi < 2; ++mi)
#pragma unroll
            for (int nti = 0; nti < 8; ++nti) acc[mi][nti] = (float4v){0.f, 0.f, 0.f, 0.f};

        for (int kt = 0; kt < 16; ++kt) {
            half8v a0 = *(const half8v*)(gA + l15 * 520 + kt * 32 + quad * 8);
            half8v a1 = *(const half8v*)(gA + (16 + l15) * 520 + kt * 32 + quad * 8);
#pragma unroll
            for (int nti = 0; nti < 8; ++nti) {
                half8v bb = *(const half8v*)(Wg16B + (((w * 8 + nti) * 16 + kt) * 64 + lane) * 8);
                acc[0][nti] = __builtin_amdgcn_mfma_f32_16x16x32_f16(a0, bb, acc[0][nti], 0, 0, 0);
                acc[1][nti] = __builtin_amdgcn_mfma_f32_16x16x32_f16(a1, bb, acc[1][nti], 0, 0, 0);
            }
        }
#pragma unroll
        for (int mi = 0; mi < 2; ++mi)
#pragma unroll
            for (int nti = 0; nti < 8; ++nti) {
                int colg = (w * 8 + nti) * 16 + l15;
#pragma unroll
                for (int r = 0; r < 4; ++r) {
                    float gv = (float)gA[(mi * 16 + quad * 4 + r) * 520 + colg];
                    acc[mi][nti][r] = fast_sigmoid(acc[mi][nti][r]) * gv;
                }
            }
        __syncthreads();
#pragma unroll
        for (int mi = 0; mi < 2; ++mi)
#pragma unroll
            for (int nti = 0; nti < 8; ++nti) {
                int colg = (w * 8 + nti) * 16 + l15;
#pragma unroll
                for (int r = 0; r < 4; ++r)
                    gA[(mi * 16 + quad * 4 + r) * 520 + colg] = (half_t)acc[mi][nti][r];
            }
        __syncthreads();

        float4v c2[2][12];
#pragma unroll
        for (int mi = 0; mi < 2; ++mi)
#pragma unroll
            for (int nt2 = 0; nt2 < 12; ++nt2) {
                float bv = bihC[(w * 12 + nt2) * 16 + l15];
                c2[mi][nt2] = (float4v){bv, bv, bv, bv};
            }

        for (int kt = 0; kt < 16; ++kt) {
            half8v a0 = *(const half8v*)(gA + l15 * 520 + kt * 32 + quad * 8);
            half8v a1 = *(const half8v*)(gA + (16 + l15) * 520 + kt * 32 + quad * 8);
#pragma unroll
            for (int nt2 = 0; nt2 < 12; ++nt2) {
                half8v bb = *(const half8v*)(Wih16B + (((w * 12 + nt2) * 16 + kt) * 64 + lane) * 8);
                c2[0][nt2] = __builtin_amdgcn_mfma_f32_16x16x32_f16(a0, bb, c2[0][nt2], 0, 0, 0);
                c2[1][nt2] = __builtin_amdgcn_mfma_f32_16x16x32_f16(a1, bb, c2[1][nt2], 0, 0, 0);
            }
        }
#pragma unroll
        for (int mi = 0; mi < 2; ++mi)
#pragma unroll
            for (int nt2 = 0; nt2 < 12; ++nt2) {
                int col = (w * 12 + nt2) * 16 + l15;
                float* dst = (col < 384) ? (xpf + col) : (xpb + col - 384);
#pragma unroll
                for (int r = 0; r < 4; ++r)
                    dst[(r0 + mi * 16 + quad * 4 + r) * 384] = c2[mi][nt2][r];
            }
        __syncthreads();   // drain xp stores before release
        if (tid == 0) {
            __hip_atomic_store(flags + FLAG_GF + gb * 64, 1u,
                               __ATOMIC_RELEASE, __HIP_MEMORY_SCOPE_AGENT);
            __hip_atomic_fetch_add(flags + FLAG_DONE + (gb & 7) * 64, 1u,
                                   __ATOMIC_RELEASE, __HIP_MEMORY_SCOPE_AGENT);
        }

    } else {
        // ================= gru (R20 form + per-macro-step gating) =================
        int ci  = (int)bid - 640;
        int dir = ci >> 3;
        int b   = ci & 7;
        const float* xp  = dir ? xpb  : xpf;
        const float* bhh = dir ? bhhb : bhhf;
        const half_t* wbase = whh16 + dir * 3 * TO * TO;

        half_t (*hb)[TO] = (half_t (*)[TO])smem;      // 2*128 halfs = 512B
        int* gsh = (int*)(smem + 512);

        int o = tid >> 1, hf = tid & 1;

        half8v wr[8], wz[8], wn[8];
        {
            const half_t* pr = wbase + (o)          * TO + hf * 64;
            const half_t* pz = wbase + (TO + o)     * TO + hf * 64;
            const half_t* pn = wbase + (2 * TO + o) * TO + hf * 64;
            asm volatile(
                "global_load_dwordx4 %0,  %24, off\n\t"
                "global_load_dwordx4 %1,  %24, off offset:16\n\t"
                "global_load_dwordx4 %2,  %24, off offset:32\n\t"
                "global_load_dwordx4 %3,  %24, off offset:48\n\t"
                "global_load_dwordx4 %4,  %24, off offset:64\n\t"
                "global_load_dwordx4 %5,  %24, off offset:80\n\t"
                "global_load_dwordx4 %6,  %24, off offset:96\n\t"
                "global_load_dwordx4 %7,  %24, off offset:112\n\t"
                "global_load_dwordx4 %8,  %25, off\n\t"
                "global_load_dwordx4 %9,  %25, off offset:16\n\t"
                "global_load_dwordx4 %10, %25, off offset:32\n\t"
                "global_load_dwordx4 %11, %25, off offset:48\n\t"
                "global_load_dwordx4 %12, %25, off offset:64\n\t"
                "global_load_dwordx4 %13, %25, off offset:80\n\t"
                "global_load_dwordx4 %14, %25, off offset:96\n\t"
                "global_load_dwordx4 %15, %25, off offset:112\n\t"
                "global_load_dwordx4 %16, %26, off\n\t"
                "global_load_dwordx4 %17, %26, off offset:16\n\t"
                "global_load_dwordx4 %18, %26, off offset:32\n\t"
                "global_load_dwordx4 %19, %26, off offset:48\n\t"
                "global_load_dwordx4 %20, %26, off offset:64\n\t"
                "global_load_dwordx4 %21, %26, off offset:80\n\t"
                "global_load_dwordx4 %22, %26, off offset:96\n\t"
                "global_load_dwordx4 %23, %26, off offset:112\n\t"
                "s_waitcnt vmcnt(0)"
                : "=&v"(wr[0]), "=&v"(wr[1]), "=&v"(wr[2]), "=&v"(wr[3]),
                  "=&v"(wr[4]), "=&v"(wr[5]), "=&v"(wr[6]), "=&v"(wr[7]),
                  "=&v"(wz[0]), "=&v"(wz[1]), "=&v"(wz[2]), "=&v"(wz[3]),
                  "=&v"(wz[4]), "=&v"(wz[5]), "=&v"(wz[6]), "=&v"(wz[7]),
                  "=&v"(wn[0]), "=&v"(wn[1]), "=&v"(wn[2]), "=&v"(wn[3]),
                  "=&v"(wn[4]), "=&v"(wn[5]), "=&v"(wn[6]), "=&v"(wn[7])
                : "v"(pr), "v"(pz), "v"(pn));
        }

        float br = 0.f, bz = 0.f, bn = 0.f, h = 0.f;
        if (hf == 0) {
            br = bhh[o]; bz = bhh[TO + o]; bn = bhh[2 * TO + o];
        }
        if (tid < TO) hb[0][tid] = (half_t)0.0f;
        if (tid == 0) *gsh = 0;
        __syncthreads();

        float xrv[8], xzv[8], xnv[8], hist[8];
        bool alldone = false;

        for (int S = 0; S < TP; S += 8) {
            if (!alldone) {
                if (tid == 0) {
                    int tnlo = dir ? (TP - 8 - S) : S;
                    int gb0 = tnlo >> 2, gb1 = (tnlo + 7) >> 2;
                    for (;;) {
                        unsigned sum = 0;
#pragma unroll
                        for (int q = 0; q < 8; ++q)
                            sum += __hip_atomic_load(flags + FLAG_DONE + q * 64,
                                                     __ATOMIC_ACQUIRE, __HIP_MEMORY_SCOPE_AGENT);
                        if (sum == 128u) { *gsh = 1; break; }
                        if (__hip_atomic_load(flags + FLAG_GF + gb0 * 64,
                                              __ATOMIC_ACQUIRE, __HIP_MEMORY_SCOPE_AGENT) &&
                            __hip_atomic_load(flags + FLAG_GF + gb1 * 64,
                                              __ATOMIC_ACQUIRE, __HIP_MEMORY_SCOPE_AGENT)) break;
                        __builtin_amdgcn_s_sleep(16);
                    }
                }
                __syncthreads();
                alldone = (*gsh != 0);
            }
            if (hf == 0) {
#pragma unroll
                for (int u = 0; u < 8; ++u) {
                    int s = S + u;
                    int tn = dir ? (TP - 1 - s) : s;
                    const float* xpt = xp + (tn * TB + b) * 384;
                    xrv[u] = xpt[o]; xzv[u] = xpt[TO + o]; xnv[u] = xpt[2 * TO + o];
                }
            }
#pragma unroll
            for (int u = 0; u < 8; ++u) {
                int s = S + u;
                int cur = s & 1;
                const half8v* h8 = (const half8v*)(&hb[cur][hf * 64]);
                half8v hv0 = h8[0], hv1 = h8[1], hv2 = h8[2], hv3 = h8[3];
                half8v hv4 = h8[4], hv5 = h8[5], hv6 = h8[6], hv7 = h8[7];

                float ar = 0.f, az = 0.f, an = 0.f;
                dot3_h8(wr[0], wz[0], wn[0], hv0, ar, az, an);
                dot3_h8(wr[1], wz[1], wn[1], hv1, ar, az, an);
                dot3_h8(wr[2], wz[2], wn[2], hv2, ar, az, an);
                dot3_h8(wr[3], wz[3], wn[3], hv3, ar, az, an);
                dot3_h8(wr[4], wz[4], wn[4], hv4, ar, az, an);
                dot3_h8(wr[5], wz[5], wn[5], hv5, ar, az, an);
                dot3_h8(wr[6], wz[6], wn[6], hv6, ar, az, an);
                dot3_h8(wr[7], wz[7], wn[7], hv7, ar, az, an);

                ar = pair_sum_dpp(ar);
                az = pair_sum_dpp(az);
                an = pair_sum_dpp(an);
                if (hf == 0) {
                    float r = fast_sigmoid(xrv[u] + ar + br);
                    float z = fast_sigmoid(xzv[u] + az + bz);
                    float n = fast_tanh(xnv[u] + r * (an + bn));
                    h = (1.0f - z) * n + z * h;
                    hb[cur ^ 1][o] = (half_t)h;
                    hist[u] = h;
                }
                asm volatile("s_waitcnt lgkmcnt(0)" ::: "memory");
                __builtin_amdgcn_s_barrier();
            }
            if (hf == 0) {
#pragma unroll
                for (int u = 0; u < 8; ++u) {
                    int s = S + u;
                    int t = dir ? (TP - 1 - s) : s;
                    out[(t * TB + b) * 256 + dir * TO + o] = hist[u];
                }
            }
        }
    }
}

extern "C" void kernel_launch(void* const* d_in, const int* in_sizes, int n_in,
                              void* d_out, int out_size, void* d_ws, size_t ws_size,
                              hipStream_t stream) {
    const float* v    = (const float*)d_in[0];
    const float* Wvp1 = (const float*)d_in[1];
    const float* Wvp2 = (const float*)d_in[2];
    const float* vw   = (const float*)d_in[3];
    const float* Wg   = (const float*)d_in[4];
    const float* wihf = (const float*)d_in[5];
    const float* whhf = (const float*)d_in[6];
    const float* bihf = (const float*)d_in[7];
    const float* bhhf = (const float*)d_in[8];
    const float* wihb = (const float*)d_in[9];
    const float* whhb = (const float*)d_in[10];
    const float* bihb = (const float*)d_in[11];
    const float* bhhb = (const float*)d_in[12];

    float* ws   = (float*)d_ws;
    float* bihC = ws;                    // 768 f32
    float* Wv1  = bihC + 768;            // 8*512*80 = 327680
    float* Wv2T = Wv1 + 327680;          // 8*80*512 = 327680 (transposed)
    float* xpf  = Wv2T + 327680;         // 4096*384 = 1572864
    float* xpb  = xpf + 1572864;         // 1572864
    half_t* g16    = (half_t*)(xpb + 1572864);  // 4096*512   = 2097152 halfs
    half_t* Wg16B  = g16 + 2097152;             // 262144
    half_t* Wih16B = Wg16B + 262144;            // 393216
    half_t* whh16  = Wih16B + 393216;           // 98304
    half_t* v16    = whh16 + 98304;             // 1048576
    half_t* WT16B  = v16 + 1048576;             // 40960
    half_t* vT16   = WT16B + 40960;             // 8*256*512  = 1048576
    unsigned* flags = (unsigned*)(vT16 + 1048576); // 12800 uints (padded flags)
    float* out  = (float*)d_out;

    // prep: 907 work blocks (8 elems/thread) + 256 vtrans = 1163 blocks
    prep_kernel<<<1163, 256, 0, stream>>>(v, Wvp1, Wvp2, Wg, wihf, wihb, bihf, bihb,
                                          whhf, whhb, bihC, v16, g16,
                                          Wg16B, Wih16B, whh16, WT16B, vT16, flags);
    wv12_kernel<<<256, 128, 0, stream>>>(v16, WT16B, Wv1, Wv2T);
    tail_kernel<<<656, 256, 0, stream>>>(Wv1, Wv2T, vw, vT16, g16,
                                         Wg16B, Wih16B, bihC, xpf, xpb,
                                         whh16, bhhf, bhhb, out, flags);
}

// Round 15
// 412.368 us; speedup vs baseline: 1.3480x; 1.3480x over previous
//
#include <hip/hip_runtime.h>

// Problem constants
#define TP 512   // passage length
#define TB 8     // batch
#define TD 256   // input size
#define TH 75    // attn hidden
#define THP 80   // padded attn hidden (float4-friendly, pads zeroed)
#define TO 128   // GRU hidden

// 2*log2(e): folded into Wv1/Wv2T by wv12 so score's sigmoid uses raw v_exp_f32
#define LOG2E2 2.8853900817779268f

typedef _Float16 half_t;
typedef _Float16 half2v __attribute__((ext_vector_type(2)));
typedef _Float16 half4v __attribute__((ext_vector_type(4)));
typedef _Float16 half8v __attribute__((ext_vector_type(8)));
typedef float    float4v __attribute__((ext_vector_type(4)));

__device__ __forceinline__ float fast_rcp(float x) { return __builtin_amdgcn_rcpf(x); }
__device__ __forceinline__ float ex2(float x) {
#if __has_builtin(__builtin_amdgcn_exp2f)
    return __builtin_amdgcn_exp2f(x);
#else
    float r; asm("v_exp_f32 %0, %1" : "=v"(r) : "v"(x)); return r;
#endif
}
__device__ __forceinline__ float fast_tanh(float x) {
    return 1.0f - 2.0f * fast_rcp(1.0f + __expf(2.0f * x));
}
__device__ __forceinline__ float fast_sigmoid(float x) {
    return fast_rcp(1.0f + __expf(-x));
}
__device__ __forceinline__ float fdot2h(half2v a, half2v b, float c) {
#if __has_builtin(__builtin_amdgcn_fdot2)
    return __builtin_amdgcn_fdot2(a, b, c, false);
#else
    return c + (float)a[0] * (float)b[0] + (float)a[1] * (float)b[1];
#endif
}
// aliasing-safe half2 extraction from half8v: sub-register, no punning
#define EXT2(v, j) __builtin_shufflevector((v), (v), 2*(j), 2*(j)+1)
// 3-gate dot over one 8-half chunk (4 half2 pairs per gate)
__device__ __forceinline__ void dot3_h8(half8v wr, half8v wz, half8v wn, half8v h,
                                        float& ar, float& az, float& an) {
    half2v h0 = EXT2(h, 0), h1 = EXT2(h, 1), h2 = EXT2(h, 2), h3 = EXT2(h, 3);
    ar = fdot2h(EXT2(wr, 0), h0, ar);
    az = fdot2h(EXT2(wz, 0), h0, az);
    an = fdot2h(EXT2(wn, 0), h0, an);
    ar = fdot2h(EXT2(wr, 1), h1, ar);
    az = fdot2h(EXT2(wz, 1), h1, az);
    an = fdot2h(EXT2(wn, 1), h1, an);
    ar = fdot2h(EXT2(wr, 2), h2, ar);
    az = fdot2h(EXT2(wz, 2), h2, az);
    an = fdot2h(EXT2(wn, 2), h2, an);
    ar = fdot2h(EXT2(wr, 3), h3, ar);
    az = fdot2h(EXT2(wz, 3), h3, az);
    an = fdot2h(EXT2(wn, 3), h3, an);
}
// adjacent-lane (xor-1) butterfly sum via DPP quad_perm [1,0,3,2] (VALU pipe).
__device__ __forceinline__ float pair_sum_dpp(float v) {
    int i1 = __builtin_amdgcn_update_dpp(0, __builtin_bit_cast(int, v), 0xB1, 0xF, 0xF, true);
    return v + __builtin_bit_cast(float, i1);
}
__device__ __forceinline__ half8v cvt8(float4 f0, float4 f1) {
    return (half8v){(half_t)f0.x,(half_t)f0.y,(half_t)f0.z,(half_t)f0.w,
                    (half_t)f1.x,(half_t)f1.y,(half_t)f1.z,(half_t)f1.w};
}

// ------- prep: 8 elems/thread (R26) + fused vtrans ---------------------------
// R22 decomposition showed prep ~50us at a ~10us traffic roofline -> the 7459
// trivial blocks were dispatch-rate-bound. Now 901 work blocks (8 consecutive
// elements per thread, float4x2 -> half8, numerically validated in R25) + 256
// vtrans blocks = 1157 total.
// B-frag layout (mfma_f32_16x16x32_f16): [nt][kt][lane][j] halfs with
// B[k = kt*32 + (lane>>4)*8 + j][n = nt*16 + (lane&15)]  (verified R5/R6).
__global__ __launch_bounds__(256) void prep_kernel(
    const float* __restrict__ v,
    const float* __restrict__ Wvp1, const float* __restrict__ Wvp2,
    const float* __restrict__ Wg,   const float* __restrict__ wihf,
    const float* __restrict__ wihb, const float* __restrict__ bihf,
    const float* __restrict__ bihb, const float* __restrict__ whhf,
    const float* __restrict__ whhb,
    float* __restrict__ bihC,
    half_t* __restrict__ v16, half_t* __restrict__ g16,
    half_t* __restrict__ Wg16B, half_t* __restrict__ Wih16B,
    half_t* __restrict__ whh16, half_t* __restrict__ WT16B,
    half_t* __restrict__ vT16)
{
    __shared__ half_t lt[64 * 66];   // vtrans tile [d_local][p_local], stride 66

    if (blockIdx.x >= 901) {                     // ---- fused vtrans blocks ----
        int vb = blockIdx.x - 901;               // 0..255
        int t = threadIdx.x;
        int b  = vb >> 5;
        int pt = (vb >> 2) & 7;
        int dt = vb & 3;
        {
            int pl = t >> 2, dseg = (t & 3) * 16;
            const float4* src = (const float4*)(v + (((pt * 64 + pl) * 8 + b) << 8) + dt * 64 + dseg);
            float4 f0 = src[0], f1 = src[1], f2 = src[2], f3 = src[3];
            half_t hv[16] = {
                (half_t)f0.x,(half_t)f0.y,(half_t)f0.z,(half_t)f0.w,
                (half_t)f1.x,(half_t)f1.y,(half_t)f1.z,(half_t)f1.w,
                (half_t)f2.x,(half_t)f2.y,(half_t)f2.z,(half_t)f2.w,
                (half_t)f3.x,(half_t)f3.y,(half_t)f3.z,(half_t)f3.w };
#pragma unroll
            for (int u = 0; u < 16; ++u) lt[(dseg + u) * 66 + pl] = hv[u];
        }
        __syncthreads();
        {
            int dl = t >> 2, pseg = (t & 3) * 16;
            half8v h0 = *(const half8v*)(lt + dl * 66 + pseg);
            half8v h1 = *(const half8v*)(lt + dl * 66 + pseg + 8);
            half8v* dst = (half8v*)(vT16 + ((b * 256 + dt * 64 + dl) << 9) + pt * 64 + pseg);
            dst[0] = h0; dst[1] = h1;
        }
        return;
    }

    int t8 = blockIdx.x * 256 + threadIdx.x;     // task id (8 elems each)
    if (t8 < 131072) {                           // v cast + g16 first half
        int base = t8 * 8;
        const float4* vp = (const float4*)(v + base);
        half8v hv = cvt8(vp[0], vp[1]);
        *(half8v*)(v16 + base) = hv;
        int row = base >> 8, d0 = base & 255;
        *(half8v*)(g16 + row * 512 + d0) = hv;
        return;
    }
    t8 -= 131072;
    if (t8 < 96) {                               // bihC concat
        int base = t8 * 8;
#pragma unroll
        for (int u = 0; u < 8; ++u) {
            int id = base + u;
            bihC[id] = (id < 384) ? bihf[id] : bihb[id - 384];
        }
        return;
    }
    t8 -= 96;
    if (t8 < 32768) {                            // Wg16B frags (8 j's = 8 consec k's)
        int base = t8 * 8;
        int lane = (base >> 3) & 63, kt = (base >> 9) & 15, nt = base >> 13;
        int o = nt * 16 + (lane & 15);
        int k0 = kt * 32 + ((lane >> 4) << 3);
        const float4* sp = (const float4*)(Wg + o * 512 + k0);
        *(half8v*)(Wg16B + base) = cvt8(sp[0], sp[1]);
        return;
    }
    t8 -= 32768;
    if (t8 < 49152) {                            // Wih16B frags
        int base = t8 * 8;
        int lane = (base >> 3) & 63, kt = (base >> 9) & 15, nt = base >> 13;
        int o = nt * 16 + (lane & 15);
        int k0 = kt * 32 + ((lane >> 4) << 3);
        const float4* sp = (const float4*)(((o < 384) ? (wihf + o * 512) : (wihb + (o - 384) * 512)) + k0);
        *(half8v*)(Wih16B + base) = cvt8(sp[0], sp[1]);
        return;
    }
    t8 -= 49152;
    if (t8 < 12288) {                            // whh16 linear copy
        int base = t8 * 8;
        int d = (base >= 49152) ? 1 : 0;
        int i0 = base - d * 49152;
        const float4* sp = (const float4*)((d ? whhb : whhf) + i0);
        *(half8v*)(whh16 + base) = cvt8(sp[0], sp[1]);
        return;
    }
    t8 -= 12288;
    if (t8 < 5120) {                             // WT16B frags [Wvp1;Wvp2]
        int base = t8 * 8;
        int lane = (base >> 3) & 63, kt = (base >> 9) & 7, nt = base >> 12;
        int o = nt * 16 + (lane & 15);
        int k0 = kt * 32 + ((lane >> 4) << 3);
        half8v hv = (half8v){(half_t)0,(half_t)0,(half_t)0,(half_t)0,
                             (half_t)0,(half_t)0,(half_t)0,(half_t)0};
        if (o < 75) {
            const float4* sp = (const float4*)(Wvp1 + o * 256 + k0);
            hv = cvt8(sp[0], sp[1]);
        } else if (o < 150) {
            const float4* sp = (const float4*)(Wvp2 + (o - 75) * 256 + k0);
            hv = cvt8(sp[0], sp[1]);
        }
        *(half8v*)(WT16B + base) = hv;
    }
}

// ---------------- Wv1/Wv2T via MFMA: [4096,160] = v16 @ WT16B ---------------
// 256 blocks x 128 threads (16 rows/block, 2 waves x 5 nt). Output scaled by
// 2*log2e so score's inner sigmoid is raw exp2 - numerically identical.
__global__ __launch_bounds__(128) void wv12_kernel(
    const half_t* __restrict__ v16, const half_t* __restrict__ WT16B,
    float* __restrict__ Wv1, float* __restrict__ Wv2T)
{
    int tid = threadIdx.x;
    int lane = tid & 63, w = tid >> 6;       // w in {0,1}: nt range w*5..w*5+4
    int l15 = lane & 15, quad = lane >> 4;
    int r0 = blockIdx.x * 16;

    float4v acc[5];
#pragma unroll
    for (int n5 = 0; n5 < 5; ++n5) acc[n5] = (float4v){0.f, 0.f, 0.f, 0.f};

#pragma unroll
    for (int kt = 0; kt < 8; ++kt) {
        half8v a = *(const half8v*)(v16 + (r0 + l15) * 256 + kt * 32 + quad * 8);
#pragma unroll
        for (int n5 = 0; n5 < 5; ++n5) {
            int nt = w * 5 + n5;
            half8v b = *(const half8v*)(WT16B + ((nt * 8 + kt) * 64 + lane) * 8);
            acc[n5] = __builtin_amdgcn_mfma_f32_16x16x32_f16(a, b, acc[n5], 0, 0, 0);
        }
    }
#pragma unroll
    for (int n5 = 0; n5 < 5; ++n5) {
        int col = (w * 5 + n5) * 16 + l15;
#pragma unroll
        for (int r = 0; r < 4; ++r) {
            int row = r0 + quad * 4 + r;
            int p = row >> 3, b = row & 7;
            int ob = (b * TP + p) * THP;
            float val2 = LOG2E2 * acc[n5][r];
            if (col < 75)       Wv1[ob + col] = val2;
            else if (col < 80)  { Wv1[ob + col] = 0.0f;
                                  Wv2T[(b * THP + col - 75) * TP + p] = val2; }
            else if (col < 150) Wv2T[(b * THP + col - 75) * TP + p] = val2;
            else if (col < 155) Wv2T[(b * THP + col - 75) * TP + p] = 0.0f;
        }
    }
}

// -- scores -> softmax(i) -> (fused) context: c[j,b,d] = sum_i a[j,i]v[i,b,d] --
// R24 form (validated): context fused into score; a-rows stay in LDS; no a16
// buffer. PV via the proven context MFMA loop, C-store masked to j_local<8.
__global__ __launch_bounds__(256) void score_kernel(
    const float* __restrict__ Wv1, const float* __restrict__ Wv2T,
    const float* __restrict__ vw, const half_t* __restrict__ vT16,
    half_t* __restrict__ g16)
{
    int tid = threadIdx.x;
    int b  = blockIdx.x >> 6;
    int j0 = (blockIdx.x & 63) * 8;
    __shared__ float wv1j[8 * THP];
    __shared__ float vws[THP];
    __shared__ float sc[8 * TP];
    __shared__ __align__(16) half_t aL[16 * 528];   // A-tile, rows 8..15 zero

    int lane = tid & 63, w = tid >> 6;
    int l15 = lane & 15, quad = lane >> 4;

    // zero the pad rows 8..15 (covered by the first __syncthreads)
    for (int e = tid; e < 8 * 528; e += 256) aL[8 * 528 + e] = (half_t)0.0f;

    if (tid < THP) vws[tid] = (tid < TH) ? vw[tid] : 0.0f;
    for (int e = tid; e < 8 * THP; e += 256) {
        int jj = e / THP, k = e - jj * THP;
        wv1j[e] = Wv1[(b * TP + j0 + jj) * THP + k];
    }
    __syncthreads();

    float Csum = 0.0f;
    {
        const float4* c4 = (const float4*)vws;
        for (int kk = 0; kk < 20; ++kk) { float4 c = c4[kk]; Csum += c.x + c.y + c.z + c.w; }
    }

    int i0 = tid, i1 = tid + 256;
    float acc0[8] = {0.f,0.f,0.f,0.f,0.f,0.f,0.f,0.f};
    float acc1[8] = {0.f,0.f,0.f,0.f,0.f,0.f,0.f,0.f};
    const float* wvt = Wv2T + b * THP * TP;
#pragma unroll
    for (int kt = 0; kt < 5; ++kt) {
        float r0v[16], r1v[16];
#pragma unroll
        for (int u = 0; u < 16; ++u) {
            const float* colp = wvt + (kt * 16 + u) * TP;
            r0v[u] = colp[i0];
            r1v[u] = colp[i1];
        }
        const float* cp = vws + kt * 16;
#pragma unroll
        for (int jj = 0; jj < 8; ++jj) {
            const float* w1 = wv1j + jj * THP + kt * 16;
            float s0 = 0.f, s1 = 0.f;
#pragma unroll
            for (int u = 0; u < 16; ++u) {
                float cu = cp[u], wu = w1[u];
                s0 += cu * fast_rcp(1.0f + ex2(r0v[u] + wu));
                s1 += cu * fast_rcp(1.0f + ex2(r1v[u] + wu));
            }
            acc0[jj] += s0; acc1[jj] += s1;
        }
    }
#pragma unroll
    for (int jj = 0; jj < 8; ++jj) {
        sc[jj * TP + i0] = Csum - 2.0f * acc0[jj];
        sc[jj * TP + i1] = Csum - 2.0f * acc1[jj];
    }
    __syncthreads();

#pragma unroll
    for (int ps = 0; ps < 2; ++ps) {
        int jj = (tid >> 6) + ps * 4, l = tid & 63;
        float m = -1e30f;
#pragma unroll
        for (int q = 0; q < 8; ++q) m = fmaxf(m, sc[jj * TP + l + q * 64]);
#pragma unroll
        for (int s = 32; s > 0; s >>= 1) m = fmaxf(m, __shfl_xor(m, s));
        float e[8];
        float sum = 0.0f;
#pragma unroll
        for (int q = 0; q < 8; ++q) { e[q] = __expf(sc[jj * TP + l + q * 64] - m); sum += e[q]; }
#pragma unroll
        for (int s = 32; s > 0; s >>= 1) sum += __shfl_xor(sum, s);
        float inv = fast_rcp(sum);
#pragma unroll
        for (int q = 0; q < 8; ++q) aL[jj * 528 + l + q * 64] = (half_t)(e[q] * inv);
    }
    __syncthreads();

    // ---- fused context: per wave w, d-tiles (w*4+nti)*16 ----
    {
        const half_t* vbase = vT16 + ((b * 256) << 9);
        float4v acc[4];
#pragma unroll
        for (int nti = 0; nti < 4; ++nti) acc[nti] = (float4v){0.f, 0.f, 0.f, 0.f};

#pragma unroll 4
        for (int kt = 0; kt < 16; ++kt) {
            half8v a = *(const half8v*)(aL + l15 * 528 + kt * 32 + quad * 8);
#pragma unroll
            for (int nti = 0; nti < 4; ++nti) {
                int d = (w * 4 + nti) * 16 + l15;
                half8v bb = *(const half8v*)(vbase + (d << 9) + kt * 32 + quad * 8);
                acc[nti] = __builtin_amdgcn_mfma_f32_16x16x32_f16(a, bb, acc[nti], 0, 0, 0);
            }
        }
        int jl0 = quad * 4;
        if (jl0 < 8) {                     // quad 0/1 hold the 8 real rows
#pragma unroll
            for (int nti = 0; nti < 4; ++nti) {
                int d = (w * 4 + nti) * 16 + l15;
#pragma unroll
                for (int r = 0; r < 4; ++r) {
                    int j = j0 + jl0 + r;
                    g16[(j * TB + b) * 512 + 256 + d] = (half_t)acc[nti][r];
                }
            }
        }
    }
}

// -------- MFMA gate (sigmoid(g Wg^T)*g) + GRU input projections -------------
__global__ __launch_bounds__(256, 1) void gatexp_kernel(
    const half_t* __restrict__ g16, const half_t* __restrict__ Wg16B,
    const half_t* __restrict__ Wih16B, const float* __restrict__ bihC,
    float* __restrict__ xpf, float* __restrict__ xpb)
{
    __shared__ half_t gA[32 * 520];      // rows padded to 520 halfs
    int tid = threadIdx.x;
    int r0 = blockIdx.x * 32;
    int lane = tid & 63, w = tid >> 6;
    int l15 = lane & 15, quad = lane >> 4;

    for (int e = tid; e < 2048; e += 256) {
        int row = e >> 6, c8 = e & 63;
        *(half8v*)(gA + row * 520 + c8 * 8) =
            *(const half8v*)(g16 + (r0 + row) * 512 + c8 * 8);
    }
    __syncthreads();

    float4v acc[2][8];
#pragma unroll
    for (int mi = 0; mi < 2; ++mi)
#pragma unroll
        for (int nti = 0; nti < 8; ++nti) acc[mi][nti] = (float4v){0.f, 0.f, 0.f, 0.f};

    for (int kt = 0; kt < 16; ++kt) {
        half8v a0 = *(const half8v*)(gA + l15 * 520 + kt * 32 + quad * 8);
        half8v a1 = *(const half8v*)(gA + (16 + l15) * 520 + kt * 32 + quad * 8);
#pragma unroll
        for (int nti = 0; nti < 8; ++nti) {
            half8v bb = *(const half8v*)(Wg16B + (((w * 8 + nti) * 16 + kt) * 64 + lane) * 8);
            acc[0][nti] = __builtin_amdgcn_mfma_f32_16x16x32_f16(a0, bb, acc[0][nti], 0, 0, 0);
            acc[1][nti] = __builtin_amdgcn_mfma_f32_16x16x32_f16(a1, bb, acc[1][nti], 0, 0, 0);
        }
    }
#pragma unroll
    for (int mi = 0; mi < 2; ++mi)
#pragma unroll
        for (int nti = 0; nti < 8; ++nti) {
            int colg = (w * 8 + nti) * 16 + l15;
#pragma unroll
            for (int r = 0; r < 4; ++r) {
                float gv = (float)gA[(mi * 16 + quad * 4 + r) * 520 + colg];
                acc[mi][nti][r] = fast_sigmoid(acc[mi][nti][r]) * gv;
            }
        }
    __syncthreads();
#pragma unroll
    for (int mi = 0; mi < 2; ++mi)
#pragma unroll
        for (int nti = 0; nti < 8; ++nti) {
            int colg = (w * 8 + nti) * 16 + l15;
#pragma unroll
            for (int r = 0; r < 4; ++r)
                gA[(mi * 16 + quad * 4 + r) * 520 + colg] = (half_t)acc[mi][nti][r];
        }
    __syncthreads();

    float4v c2[2][12];
#pragma unroll
    for (int mi = 0; mi < 2; ++mi)
#pragma unroll
        for (int nt2 = 0; nt2 < 12; ++nt2) {
            float bv = bihC[(w * 12 + nt2) * 16 + l15];
            c2[mi][nt2] = (float4v){bv, bv, bv, bv};
        }

    for (int kt = 0; kt < 16; ++kt) {
        half8v a0 = *(const half8v*)(gA + l15 * 520 + kt * 32 + quad * 8);
        half8v a1 = *(const half8v*)(gA + (16 + l15) * 520 + kt * 32 + quad * 8);
#pragma unroll
        for (int nt2 = 0; nt2 < 12; ++nt2) {
            half8v bb = *(const half8v*)(Wih16B + (((w * 12 + nt2) * 16 + kt) * 64 + lane) * 8);
            c2[0][nt2] = __builtin_amdgcn_mfma_f32_16x16x32_f16(a0, bb, c2[0][nt2], 0, 0, 0);
            c2[1][nt2] = __builtin_amdgcn_mfma_f32_16x16x32_f16(a1, bb, c2[1][nt2], 0, 0, 0);
        }
    }
#pragma unroll
    for (int mi = 0; mi < 2; ++mi)
#pragma unroll
        for (int nt2 = 0; nt2 < 12; ++nt2) {
            int col = (w * 12 + nt2) * 16 + l15;
            float* dst = (col < 384) ? (xpf + col) : (xpb + col - 384);
#pragma unroll
            for (int r = 0; r < 4; ++r)
                dst[(r0 + mi * 16 + quad * 4 + r) * 384] = c2[mi][nt2][r];
        }
}

// ---------------- GRU recurrence, one block per (dir, batch) ----------------
// R20 form (tied-best 221us): R16 + lgkm-only step barrier. Campaign closed:
// 7 structural variants bracket a ~1040cy/step floor. Runs ALONE on the
// device (R25 proved co-scheduling the GRU with other work ~2x's its step).
__global__ __launch_bounds__(256, 1) void gru_kernel(
    const float* __restrict__ xpf, const float* __restrict__ xpb,
    const half_t* __restrict__ whh16,
    const float* __restrict__ bhhf, const float* __restrict__ bhhb,
    float* __restrict__ out)
{
    int tid = threadIdx.x;
    int dir = blockIdx.x >> 3;
    int b   = blockIdx.x & 7;
    const float* xp  = dir ? xpb  : xpf;
    const float* bhh = dir ? bhhb : bhhf;
    const half_t* wbase = whh16 + dir * 3 * TO * TO;

    __shared__ __align__(16) half_t hb[2][TO];

    int o = tid >> 1, hf = tid & 1;

    half8v wr[8], wz[8], wn[8];
    {
        const half_t* pr = wbase + (o)          * TO + hf * 64;
        const half_t* pz = wbase + (TO + o)     * TO + hf * 64;
        const half_t* pn = wbase + (2 * TO + o) * TO + hf * 64;
        asm volatile(
            "global_load_dwordx4 %0,  %24, off\n\t"
            "global_load_dwordx4 %1,  %24, off offset:16\n\t"
            "global_load_dwordx4 %2,  %24, off offset:32\n\t"
            "global_load_dwordx4 %3,  %24, off offset:48\n\t"
            "global_load_dwordx4 %4,  %24, off offset:64\n\t"
            "global_load_dwordx4 %5,  %24, off offset:80\n\t"
            "global_load_dwordx4 %6,  %24, off offset:96\n\t"
            "global_load_dwordx4 %7,  %24, off offset:112\n\t"
            "global_load_dwordx4 %8,  %25, off\n\t"
            "global_load_dwordx4 %9,  %25, off offset:16\n\t"
            "global_load_dwordx4 %10, %25, off offset:32\n\t"
            "global_load_dwordx4 %11, %25, off offset:48\n\t"
            "global_load_dwordx4 %12, %25, off offset:64\n\t"
            "global_load_dwordx4 %13, %25, off offset:80\n\t"
            "global_load_dwordx4 %14, %25, off offset:96\n\t"
            "global_load_dwordx4 %15, %25, off offset:112\n\t"
            "global_load_dwordx4 %16, %26, off\n\t"
            "global_load_dwordx4 %17, %26, off offset:16\n\t"
            "global_load_dwordx4 %18, %26, off offset:32\n\t"
            "global_load_dwordx4 %19, %26, off offset:48\n\t"
            "global_load_dwordx4 %20, %26, off offset:64\n\t"
            "global_load_dwordx4 %21, %26, off offset:80\n\t"
            "global_load_dwordx4 %22, %26, off offset:96\n\t"
            "global_load_dwordx4 %23, %26, off offset:112\n\t"
            "s_waitcnt vmcnt(0)"
            : "=&v"(wr[0]), "=&v"(wr[1]), "=&v"(wr[2]), "=&v"(wr[3]),
              "=&v"(wr[4]), "=&v"(wr[5]), "=&v"(wr[6]), "=&v"(wr[7]),
              "=&v"(wz[0]), "=&v"(wz[1]), "=&v"(wz[2]), "=&v"(wz[3]),
              "=&v"(wz[4]), "=&v"(wz[5]), "=&v"(wz[6]), "=&v"(wz[7]),
              "=&v"(wn[0]), "=&v"(wn[1]), "=&v"(wn[2]), "=&v"(wn[3]),
              "=&v"(wn[4]), "=&v"(wn[5]), "=&v"(wn[6]), "=&v"(wn[7])
            : "v"(pr), "v"(pz), "v"(pn));
    }

    float br = 0.f, bz = 0.f, bn = 0.f, h = 0.f;
    if (hf == 0) {
        br = bhh[o]; bz = bhh[TO + o]; bn = bhh[2 * TO + o];
    }
    if (tid < TO) hb[0][tid] = (half_t)0.0f;
    __syncthreads();

    float xrv[8], xzv[8], xnv[8], hist[8];

    for (int S = 0; S < TP; S += 8) {
        // batch-issue 24 xp loads for steps S..S+7 (hf==0 lanes)
        if (hf == 0) {
#pragma unroll
            for (int u = 0; u < 8; ++u) {
                int s = S + u;
                int tn = dir ? (TP - 1 - s) : s;
                const float* xpt = xp + (tn * TB + b) * 384;
                xrv[u] = xpt[o]; xzv[u] = xpt[TO + o]; xnv[u] = xpt[2 * TO + o];
            }
        }
#pragma unroll
        for (int u = 0; u < 8; ++u) {
            int s = S + u;
            int cur = s & 1;
            const half8v* h8 = (const half8v*)(&hb[cur][hf * 64]);
            half8v hv0 = h8[0], hv1 = h8[1], hv2 = h8[2], hv3 = h8[3];
            half8v hv4 = h8[4], hv5 = h8[5], hv6 = h8[6], hv7 = h8[7];

            float ar = 0.f, az = 0.f, an = 0.f;
            dot3_h8(wr[0], wz[0], wn[0], hv0, ar, az, an);
            dot3_h8(wr[1], wz[1], wn[1], hv1, ar, az, an);
            dot3_h8(wr[2], wz[2], wn[2], hv2, ar, az, an);
            dot3_h8(wr[3], wz[3], wn[3], hv3, ar, az, an);
            dot3_h8(wr[4], wz[4], wn[4], hv4, ar, az, an);
            dot3_h8(wr[5], wz[5], wn[5], hv5, ar, az, an);
            dot3_h8(wr[6], wz[6], wn[6], hv6, ar, az, an);
            dot3_h8(wr[7], wz[7], wn[7], hv7, ar, az, an);

            ar = pair_sum_dpp(ar);
            az = pair_sum_dpp(az);
            an = pair_sum_dpp(an);
            if (hf == 0) {
                float r = fast_sigmoid(xrv[u] + ar + br);
                float z = fast_sigmoid(xzv[u] + az + bz);
                float n = fast_tanh(xnv[u] + r * (an + bn));
                h = (1.0f - z) * n + z * h;
                hb[cur ^ 1][o] = (half_t)h;
                hist[u] = h;
            }
            // lgkm-only drain + raw barrier: LDS ordering preserved; the
            // 24 xp loads / 8 out stores stay in flight across steps.
            asm volatile("s_waitcnt lgkmcnt(0)" ::: "memory");
            __builtin_amdgcn_s_barrier();
        }
        // batch the out-stores (never drained at step barriers)
        if (hf == 0) {
#pragma unroll
            for (int u = 0; u < 8; ++u) {
                int s = S + u;
                int t = dir ? (TP - 1 - s) : s;
                out[(t * TB + b) * 256 + dir * TO + o] = hist[u];
            }
        }
    }
}

extern "C" void kernel_launch(void* const* d_in, const int* in_sizes, int n_in,
                              void* d_out, int out_size, void* d_ws, size_t ws_size,
                              hipStream_t stream) {
    const float* v    = (const float*)d_in[0];
    const float* Wvp1 = (const float*)d_in[1];
    const float* Wvp2 = (const float*)d_in[2];
    const float* vw   = (const float*)d_in[3];
    const float* Wg   = (const float*)d_in[4];
    const float* wihf = (const float*)d_in[5];
    const float* whhf = (const float*)d_in[6];
    const float* bihf = (const float*)d_in[7];
    const float* bhhf = (const float*)d_in[8];
    const float* wihb = (const float*)d_in[9];
    const float* whhb = (const float*)d_in[10];
    const float* bihb = (const float*)d_in[11];
    const float* bhhb = (const float*)d_in[12];

    float* ws   = (float*)d_ws;
    float* bihC = ws;                    // 768 f32
    float* Wv1  = bihC + 768;            // 8*512*80 = 327680
    float* Wv2T = Wv1 + 327680;          // 8*80*512 = 327680 (transposed)
    float* xpf  = Wv2T + 327680;         // 4096*384 = 1572864
    float* xpb  = xpf + 1572864;         // 1572864
    half_t* g16    = (half_t*)(xpb + 1572864);  // 4096*512   = 2097152 halfs
    half_t* Wg16B  = g16 + 2097152;             // 262144
    half_t* Wih16B = Wg16B + 262144;            // 393216
    half_t* whh16  = Wih16B + 393216;           // 98304
    half_t* v16    = whh16 + 98304;             // 1048576
    half_t* WT16B  = v16 + 1048576;             // 40960
    half_t* vT16   = WT16B + 40960;             // 8*256*512  = 1048576
    float* out  = (float*)d_out;

    // prep: 901 work blocks (8 elems/thread, 230496 tasks) + 256 vtrans = 1157
    prep_kernel<<<1157, 256, 0, stream>>>(v, Wvp1, Wvp2, Wg, wihf, wihb, bihf, bihb,
                                          whhf, whhb, bihC, v16, g16,
                                          Wg16B, Wih16B, whh16, WT16B, vT16);
    wv12_kernel<<<256, 128, 0, stream>>>(v16, WT16B, Wv1, Wv2T);
    score_kernel<<<512, 256, 0, stream>>>(Wv1, Wv2T, vw, vT16, g16);
    gatexp_kernel<<<128, 256, 0, stream>>>(g16, Wg16B, Wih16B, bihC, xpf, xpb);
    gru_kernel<<<16, 256, 0, stream>>>(xpf, xpb, whh16, bhhf, bhhb, out);
}